// Round 12
// baseline (17376.074 us; speedup 1.0000x reference)
//
#include <hip/hip_runtime.h>
#include <hip/hip_cooperative_groups.h>

// Problem constants (B=2, S=1024, I=1024, H=1024, L=2)
constexpr int HD    = 1024;       // hidden size == input size
constexpr int SEQ   = 2048;       // B*S flattened steps per layer
constexpr int NL    = 2;          // layers
constexpr int NSTEP = NL * SEQ;   // 4096 serial steps
constexpr int NBLK  = 32;         // participating CUs (32 rows each)
constexpr int TPB   = 512;        // threads per block
constexpr int RPC   = 32;         // rows per CU
constexpr int KPT   = 64;         // k-span per thread (16 threads per row)
constexpr int NMIR  = 32;         // one private mirror per CU (4 streams/line)

typedef unsigned u32x4 __attribute__((ext_vector_type(4)));

// ---------------------------------------------------------------------------
// Tagged bf16 dataflow: element = 4 B = (u16 step-tag << 16 | bf16 value);
// the sc0sc1 store is both data and readiness signal (cross-CU == MALL;
// sc0 alone is CU-scope — r9). r11 landed 1.88us/phase with hop ~1.5us.
// This round: (a) 32 mirrors -> each CU polls a PRIVATE mirror, 4 poll
// streams per 64B line (the floor); (b) 2-deep ping-pong poll -> sampling
// interval ~RT/2 with a one-time vmcnt pre-drain (vmcnt counts stores too,
// so the old single poll's vmcnt(0) serialized on our own publishes).
// ---------------------------------------------------------------------------
__device__ __forceinline__ unsigned packbf(float v, unsigned tag) {
  unsigned b = __float_as_uint(v);
  b += 0x7FFFu + ((b >> 16) & 1u);          // RNE round to bf16
  return (tag << 16) | (b >> 16);
}
__device__ __forceinline__ unsigned pack2(float a, float b) {  // 2 bf16 in u32
  unsigned ua = __float_as_uint(a); ua += 0x7FFFu + ((ua >> 16) & 1u);
  unsigned ub = __float_as_uint(b); ub += 0x7FFFu + ((ub >> 16) & 1u);
  return (ua >> 16) | (ub & 0xFFFF0000u);
}
__device__ __forceinline__ bool tags_ok(u32x4 v, unsigned tag) {
  return (v.x >> 16) == tag && (v.y >> 16) == tag &&
         (v.z >> 16) == tag && (v.w >> 16) == tag;
}
// 2-deep ping-pong poll of one 16B chunk. Pre-drain makes vmcnt counts
// clean (drains our fire-and-forget publishes + ax prefetches once, mostly
// overlapped with producer->consumer flight). sched_barrier(0) after each
// counted wait: "memory" clobber does not order register-only tag checks
// (guide rule #18).
__device__ __forceinline__ u32x4 poll4(const unsigned* p, unsigned tag) {
  u32x4 a, b;
  asm volatile("s_waitcnt vmcnt(0)" ::: "memory");        // clean the counter
  asm volatile("global_load_dwordx4 %0, %1, off sc0 sc1"
               : "=&v"(a) : "v"(p) : "memory");
  while (true) {
    asm volatile("global_load_dwordx4 %0, %1, off sc0 sc1\n\t"
                 "s_waitcnt vmcnt(1)"
                 : "=&v"(b) : "v"(p) : "memory");
    __builtin_amdgcn_sched_barrier(0);                    // 'a' valid here
    if (tags_ok(a, tag)) {
      asm volatile("s_waitcnt vmcnt(0)" ::: "memory");    // drain 'b'
      return a;
    }
    asm volatile("global_load_dwordx4 %0, %1, off sc0 sc1\n\t"
                 "s_waitcnt vmcnt(1)"
                 : "=&v"(a) : "v"(p) : "memory");
    __builtin_amdgcn_sched_barrier(0);                    // 'b' valid here
    if (tags_ok(b, tag)) {
      asm volatile("s_waitcnt vmcnt(0)" ::: "memory");    // drain 'a'
      return b;
    }
  }
}
// Wave-cooperative publish: each 16-lane row group holds one packed word wv
// (identical across the group); lanes 0..31 collect the wave's 4 row words
// and store one aligned dwordx4 to mirror #lane. Fire-and-forget.
__device__ __forceinline__ void wave_publish(unsigned* base, unsigned wv,
                                             int lane, int pubrow) {
  const unsigned w0 = __shfl(wv, 0);
  const unsigned w1 = __shfl(wv, 16);
  const unsigned w2 = __shfl(wv, 32);
  const unsigned w3 = __shfl(wv, 48);
  if (lane < NMIR) {
    u32x4 o; o.x = w0; o.y = w1; o.z = w2; o.w = w3;
    unsigned* dst = base + lane * HD + pubrow;
    asm volatile("global_store_dwordx4 %0, %1, off sc0 sc1"
                 :: "v"(dst), "v"(o) : "memory");
  }
}
// Load one gate-row k-chunk (64 fp32 from HBM) into 32 bf16-packed VGPRs.
__device__ __forceinline__ void load_gate(const float* p, unsigned (&dst)[32]) {
#pragma unroll
  for (int j = 0; j < 16; ++j) {
    const float4 v = *reinterpret_cast<const float4*>(p + 4 * j);
    dst[2 * j]     = pack2(v.x, v.y);
    dst[2 * j + 1] = pack2(v.z, v.w);
  }
}
__device__ __forceinline__ float red16(float s) {   // 16-lane butterfly: all
  s += __shfl_xor(s, 8, 16);                        // lanes end with the sum
  s += __shfl_xor(s, 4, 16);
  s += __shfl_xor(s, 2, 16);
  s += __shfl_xor(s, 1, 16);
  return s;
}
// LDS pair-index swizzle (r11): chunk c (32 pairs) gets 1 pad word -> the 16
// chunks land on distinct banks; conflict-free (r10's 4.7e8 -> 0, verified).
__device__ __forceinline__ int swz(int lp) { return lp + (lp >> 5); }
constexpr int SLDS = 16 * 33;   // 528 u32

// ---------------------------------------------------------------------------
// Phase A: Ax[gl][t][row] = X[t,:] . W_g[l][row, HD:2HD] + b_g[l][row]
// gl = l*3 + g, g in {0:r, 1:z, 2:h}. 64x64 fp32 LDS-tiled GEMM (unchanged).
// ---------------------------------------------------------------------------
__global__ void __launch_bounds__(256) ax_gemm_kernel(
    const float* __restrict__ X,
    const float* __restrict__ Wr, const float* __restrict__ Wz, const float* __restrict__ Wh,
    const float* __restrict__ br, const float* __restrict__ bz, const float* __restrict__ bh,
    float* __restrict__ ax)
{
  __shared__ float sX[16][64];   // [k][t]
  __shared__ float sW[16][64];   // [k][row]

  const int gl = blockIdx.z, l = gl / 3, g = gl % 3;
  const float* W    = (g == 0 ? Wr : (g == 1 ? Wz : Wh)) + (size_t)l * HD * (2 * HD) + HD;
  const float* bias = (g == 0 ? br : (g == 1 ? bz : bh)) + l * HD;
  const int t0 = blockIdx.y * 64, r0 = blockIdx.x * 64;
  const int tid = threadIdx.x;
  const int tx = tid & 15;
  const int ty = tid >> 4;
  const int lt = tid >> 2;
  const int lk = (tid & 3) * 4;

  float acc[4][4] = {};

  for (int k0 = 0; k0 < HD; k0 += 16) {
    float4 xv = *reinterpret_cast<const float4*>(&X[(size_t)(t0 + lt) * HD + k0 + lk]);
    float4 wv = *reinterpret_cast<const float4*>(&W[(size_t)(r0 + lt) * (2 * HD) + k0 + lk]);
    __syncthreads();
    sX[lk + 0][lt] = xv.x; sX[lk + 1][lt] = xv.y; sX[lk + 2][lt] = xv.z; sX[lk + 3][lt] = xv.w;
    sW[lk + 0][lt] = wv.x; sW[lk + 1][lt] = wv.y; sW[lk + 2][lt] = wv.z; sW[lk + 3][lt] = wv.w;
    __syncthreads();
#pragma unroll
    for (int k = 0; k < 16; ++k) {
      float4 a = *reinterpret_cast<const float4*>(&sX[k][ty * 4]);
      float4 b = *reinterpret_cast<const float4*>(&sW[k][tx * 4]);
      const float av[4] = {a.x, a.y, a.z, a.w};
      const float bv[4] = {b.x, b.y, b.z, b.w};
#pragma unroll
      for (int i = 0; i < 4; ++i)
#pragma unroll
        for (int j = 0; j < 4; ++j)
          acc[i][j] += av[i] * bv[j];
    }
  }

  float4 bb = *reinterpret_cast<const float4*>(&bias[r0 + tx * 4]);
  const float bv[4] = {bb.x, bb.y, bb.z, bb.w};
#pragma unroll
  for (int i = 0; i < 4; ++i) {
    float4 o;
    o.x = acc[i][0] + bv[0]; o.y = acc[i][1] + bv[1];
    o.z = acc[i][2] + bv[2]; o.w = acc[i][3] + bv[3];
    *reinterpret_cast<float4*>(
        &ax[((size_t)gl * SEQ + t0 + ty * 4 + i) * HD + r0 + tx * 4]) = o;
  }
}

// ---------------------------------------------------------------------------
// Phase B: 4096-step serial scan on 32 CUs, tagged dataflow.
// hpack / rhpack: [2 parity][32 mirrors][1024 u32] (256 KB each).
//   h entering step u : parity u&1, tag u   (memset 0 == step-0 init, h=0)
//   r*h of step u     : parity u&1, tag u+1
//   h leaving step u  : parity (u+1)&1, tag u+1
// Overwrite safety (r6 proof): a producer reaching a same-parity rewrite
// transitively proves every CU consumed the 2-steps-older generation.
// Thread = (row = tid>>4 of 32, kchunk = tid&15); wave owns 4 rows.
// Gate results computed redundantly by all 16 lanes of a row group
// (butterfly reduce; fp32 h-carry replicated, identical arithmetic ->
// deterministic), enabling the wave-cooperative dwordx4 publish.
// ---------------------------------------------------------------------------
__global__ void __launch_bounds__(TPB) gru_seq_kernel(
    const float* __restrict__ Wr, const float* __restrict__ Wz, const float* __restrict__ Wh,
    const float* __restrict__ ax,
    unsigned* __restrict__ hpack, unsigned* __restrict__ rhpack,
    float* __restrict__ outp)
{
  __shared__ unsigned sH[SLDS];    // staged h, bf16 pairs, swizzled
  __shared__ unsigned sRH[SLDS];   // staged r*h

  const int wg   = blockIdx.x;
  const int tid  = threadIdx.x;
  const int rloc = tid >> 4;              // 0..31 local row
  const int grow = wg * RPC + rloc;       // global row 0..1023
  const int kcIdx = tid & 15;
  const int kc   = kcIdx * KPT;           // k-chunk base
  const int lane = tid & 63;              // lane within wave
  const int wave = tid >> 6;              // 0..7
  const int pubrow = wg * RPC + wave * 4; // wave's first published row
  const bool lead = (kcIdx == 0);
  const int mymir = wg * HD;              // PRIVATE mirror per CU

  unsigned wr_[32], wz_[32], wh_[32];     // current-layer weights, bf16 x2
  auto load_layer = [&](int l) {
    const size_t off = ((size_t)l * HD + grow) * (size_t)(2 * HD) + kc;
    load_gate(Wr + off, wr_);
    load_gate(Wz + off, wz_);
    load_gate(Wh + off, wh_);
  };
  load_layer(0);

  float hreg = 0.0f;                      // fp32 h carry, replicated x16
  float zv = 0.0f;
  // ax scalars: all 16 lanes of a row group load the same address (broadcast)
  float axr  = ax[(size_t)0 * SEQ * HD + grow];
  float axz  = ax[(size_t)1 * SEQ * HD + grow];
  float axh_ = ax[(size_t)2 * SEQ * HD + grow];

  for (int u = 0; u < NSTEP; ++u) {
    if (u == SEQ) load_layer(1);          // one-time layer switch
    const int pb  = (u & 1) * NMIR * HD;
    const int pbn = ((u + 1) & 1) * NMIR * HD;

    // ---- phase 1: poll h; r-dot; publish r*h; z-dot in store shadow -----
    if (tid < 256) {
      u32x4 v = poll4(&hpack[pb + mymir + 4 * tid], (unsigned)u);
      const int lp = 2 * tid;
      sH[swz(lp)]     = (v.y << 16) | (v.x & 0xFFFFu);   // bf16 pair (lo,hi)
      sH[swz(lp + 1)] = (v.w << 16) | (v.z & 0xFFFFu);
    }
    __syncthreads();                      // S1
    {
      const unsigned* hp = &sH[kcIdx * 33];
      float sr = 0.0f;
#pragma unroll
      for (int m = 0; m < 32; ++m) {
        const unsigned hpair = hp[m];
        const unsigned a = wr_[m];
        sr = fmaf(__uint_as_float(a << 16), __uint_as_float(hpair << 16), sr);
        sr = fmaf(__uint_as_float(a & 0xFFFF0000u),
                  __uint_as_float(hpair & 0xFFFF0000u), sr);
      }
      sr = red16(sr);
      const float rg = 1.0f / (1.0f + expf(-(sr + axr)));
      wave_publish(rhpack + pb, packbf(rg * hreg, (unsigned)(u + 1)),
                   lane, pubrow);
      // z-dot runs while the r*h store flies (needed only in phase 2)
      float sz = 0.0f;
#pragma unroll
      for (int m = 0; m < 32; ++m) {
        const unsigned hpair = hp[m];
        const unsigned b = wz_[m];
        sz = fmaf(__uint_as_float(b << 16), __uint_as_float(hpair << 16), sz);
        sz = fmaf(__uint_as_float(b & 0xFFFF0000u),
                  __uint_as_float(hpair & 0xFFFF0000u), sz);
      }
      sz = red16(sz);
      zv = 1.0f / (1.0f + expf(-(sz + axz)));
    }

    // ---- phase 2: poll r*h; hh-dot; blend; publish h ----------------------
    if (tid < 256) {
      u32x4 v = poll4(&rhpack[pb + mymir + 4 * tid], (unsigned)(u + 1));
      const int lp = 2 * tid;
      sRH[swz(lp)]     = (v.y << 16) | (v.x & 0xFFFFu);
      sRH[swz(lp + 1)] = (v.w << 16) | (v.z & 0xFFFFu);
    }
    __syncthreads();                      // S2
    {
      const unsigned* rp = &sRH[kcIdx * 33];
      float sh = 0.0f;
#pragma unroll
      for (int m = 0; m < 32; ++m) {
        const unsigned rpair = rp[m];
        const unsigned c = wh_[m];
        sh = fmaf(__uint_as_float(c << 16), __uint_as_float(rpair << 16), sh);
        sh = fmaf(__uint_as_float(c & 0xFFFF0000u),
                  __uint_as_float(rpair & 0xFFFF0000u), sh);
      }
      sh = red16(sh);
      const float hh = tanhf(sh + axh_);
      const float hn = (1.0f - zv) * hreg + zv * hh;    // fp32 carry
      hreg = hn;
      wave_publish(hpack + pbn, packbf(hn, (unsigned)(u + 1)), lane, pubrow);
      if (u == NSTEP - 1 && lead) {       // (output, hidden) identical
        outp[grow] = hn;
        outp[HD + grow] = hn;
      }
      // prefetch ax for step u+1 (drained by the next poll's pre-drain,
      // overlapped with producer->consumer flight)
      const int un = (u + 1 < NSTEP) ? u + 1 : u;
      const int ln = un >> 11, tn = un & (SEQ - 1);
      axr  = ax[(((size_t)ln * 3 + 0) * SEQ + tn) * HD + grow];
      axz  = ax[(((size_t)ln * 3 + 1) * SEQ + tn) * HD + grow];
      axh_ = ax[(((size_t)ln * 3 + 2) * SEQ + tn) * HD + grow];
    }
  }
}

// ---------------------------------------------------------------------------
extern "C" void kernel_launch(void* const* d_in, const int* in_sizes, int n_in,
                              void* d_out, int out_size, void* d_ws, size_t ws_size,
                              hipStream_t stream) {
  const float* emb = (const float*)d_in[0];
  const float* Wr  = (const float*)d_in[1];
  const float* br  = (const float*)d_in[2];
  const float* Wz  = (const float*)d_in[3];
  const float* bz  = (const float*)d_in[4];
  const float* Wh  = (const float*)d_in[5];
  const float* bh  = (const float*)d_in[6];
  float* outp = (float*)d_out;

  float*    ws     = (float*)d_ws;
  float*    ax     = ws;                                  // 6*SEQ*HD fp32 = 50.3 MB
  unsigned* hpack  = (unsigned*)(ws + (size_t)6 * SEQ * HD); // [2][32][1024] u32
  unsigned* rhpack = hpack + 2 * NMIR * HD;               // [2][32][1024] u32

  // Deterministic tag state each call: zero both parities of both mirrored
  // buffers (parity-0 tag 0 == "h entering step 0", value bf16(0)).
  hipMemsetAsync(hpack, 0, 4 * NMIR * HD * sizeof(unsigned), stream);

  // Phase A: x-part contributions + bias, all gates/layers (parallel GEMM)
  dim3 g1(HD / 64, SEQ / 64, 6);
  ax_gemm_kernel<<<g1, 256, 0, stream>>>(emb, Wr, Wz, Wh, br, bz, bh, ax);

  // Phase B: serial scan on 32 CUs (trivially co-resident; cooperative
  // launch keeps the guarantee explicit).
  void* args[] = {(void*)&Wr, (void*)&Wz, (void*)&Wh, (void*)&ax,
                  (void*)&hpack, (void*)&rhpack, (void*)&outp};
  hipLaunchCooperativeKernel((const void*)gru_seq_kernel, dim3(NBLK), dim3(TPB),
                             args, 0, stream);
}

// Round 13
// 14533.087 us; speedup vs baseline: 1.1956x; 1.1956x over previous
//
#include <hip/hip_runtime.h>
#include <hip/hip_cooperative_groups.h>

// Problem constants (B=2, S=1024, I=1024, H=1024, L=2)
constexpr int HD    = 1024;       // hidden size == input size
constexpr int SEQ   = 2048;       // B*S flattened steps per layer
constexpr int NL    = 2;          // layers
constexpr int NSTEP = NL * SEQ;   // 4096 serial steps
constexpr int NBLK  = 32;         // participating CUs (32 rows each)
constexpr int TPB   = 512;        // threads per block
constexpr int RPC   = 32;         // rows per CU
constexpr int KPT   = 64;         // k-span per thread (16 threads per row)
constexpr int NMIR  = 8;          // mirrors (r11 config: 4 CUs poll each)

typedef unsigned u32x4 __attribute__((ext_vector_type(4)));

// ---------------------------------------------------------------------------
// Tagged bf16 dataflow (r11 config + 2-deep poll ONLY — bisect of r12).
// Element = 4 B = (u16 step-tag << 16 | bf16 value); the sc0sc1 store is
// both data and readiness signal (cross-CU == MALL; sc0 alone is CU-scope).
// r12 lesson: 32-mirror publish 4x'd WRITE and regressed -> keep 8 mirrors.
// This round isolates the sampling-quantization term: 2-deep ping-pong poll
// samples every ~RT/2. Pre-drain is required: stores count in vmcnt on
// gfx9-lineage, so a counted vmcnt(1) with dirty store counts would release
// before the poll load lands.
// ---------------------------------------------------------------------------
__device__ __forceinline__ unsigned packbf(float v, unsigned tag) {
  unsigned b = __float_as_uint(v);
  b += 0x7FFFu + ((b >> 16) & 1u);          // RNE round to bf16
  return (tag << 16) | (b >> 16);
}
__device__ __forceinline__ unsigned pack2(float a, float b) {  // 2 bf16 in u32
  unsigned ua = __float_as_uint(a); ua += 0x7FFFu + ((ua >> 16) & 1u);
  unsigned ub = __float_as_uint(b); ub += 0x7FFFu + ((ub >> 16) & 1u);
  return (ua >> 16) | (ub & 0xFFFF0000u);
}
__device__ __forceinline__ bool tags_ok(u32x4 v, unsigned tag) {
  return (v.x >> 16) == tag && (v.y >> 16) == tag &&
         (v.z >> 16) == tag && (v.w >> 16) == tag;
}
// 2-deep ping-pong poll of one 16B chunk: two loads in flight, counted
// vmcnt(1) -> sampling interval ~RT/2. sched_barrier(0) after each counted
// wait ("memory" clobber does not order register-only tag checks, rule #18).
__device__ __forceinline__ u32x4 poll4(const unsigned* p, unsigned tag) {
  u32x4 a, b;
  asm volatile("s_waitcnt vmcnt(0)" ::: "memory");        // clean counter
  asm volatile("global_load_dwordx4 %0, %1, off sc0 sc1"
               : "=&v"(a) : "v"(p) : "memory");
  while (true) {
    asm volatile("global_load_dwordx4 %0, %1, off sc0 sc1\n\t"
                 "s_waitcnt vmcnt(1)"
                 : "=&v"(b) : "v"(p) : "memory");
    __builtin_amdgcn_sched_barrier(0);                    // 'a' valid here
    if (tags_ok(a, tag)) {
      asm volatile("s_waitcnt vmcnt(0)" ::: "memory");    // drain 'b'
      return a;
    }
    asm volatile("global_load_dwordx4 %0, %1, off sc0 sc1\n\t"
                 "s_waitcnt vmcnt(1)"
                 : "=&v"(a) : "v"(p) : "memory");
    __builtin_amdgcn_sched_barrier(0);                    // 'b' valid here
    if (tags_ok(b, tag)) {
      asm volatile("s_waitcnt vmcnt(0)" ::: "memory");    // drain 'a'
      return b;
    }
  }
}
// Wave-cooperative publish (r11): each 16-lane row group holds one packed
// word wv (identical across the group); lanes 0..7 collect the wave's 4 row
// words and store one aligned dwordx4 to mirror #lane. Fire-and-forget.
__device__ __forceinline__ void wave_publish(unsigned* base, unsigned wv,
                                             int lane, int pubrow) {
  const unsigned w0 = __shfl(wv, 0);
  const unsigned w1 = __shfl(wv, 16);
  const unsigned w2 = __shfl(wv, 32);
  const unsigned w3 = __shfl(wv, 48);
  if (lane < NMIR) {
    u32x4 o; o.x = w0; o.y = w1; o.z = w2; o.w = w3;
    unsigned* dst = base + lane * HD + pubrow;
    asm volatile("global_store_dwordx4 %0, %1, off sc0 sc1"
                 :: "v"(dst), "v"(o) : "memory");
  }
}
// Load one gate-row k-chunk (64 fp32 from HBM) into 32 bf16-packed VGPRs.
__device__ __forceinline__ void load_gate(const float* p, unsigned (&dst)[32]) {
#pragma unroll
  for (int j = 0; j < 16; ++j) {
    const float4 v = *reinterpret_cast<const float4*>(p + 4 * j);
    dst[2 * j]     = pack2(v.x, v.y);
    dst[2 * j + 1] = pack2(v.z, v.w);
  }
}
__device__ __forceinline__ float red16(float s) {   // 16-lane butterfly: all
  s += __shfl_xor(s, 8, 16);                        // lanes end with the sum
  s += __shfl_xor(s, 4, 16);
  s += __shfl_xor(s, 2, 16);
  s += __shfl_xor(s, 1, 16);
  return s;
}
// LDS pair-index swizzle (r11): chunk c (32 pairs) gets 1 pad word -> the 16
// chunks land on distinct banks; conflict-free (r10's 4.7e8 -> 0, verified).
__device__ __forceinline__ int swz(int lp) { return lp + (lp >> 5); }
constexpr int SLDS = 16 * 33;   // 528 u32

// ---------------------------------------------------------------------------
// Phase A: Ax[gl][t][row] = X[t,:] . W_g[l][row, HD:2HD] + b_g[l][row]
// gl = l*3 + g, g in {0:r, 1:z, 2:h}. 64x64 fp32 LDS-tiled GEMM (unchanged).
// ---------------------------------------------------------------------------
__global__ void __launch_bounds__(256) ax_gemm_kernel(
    const float* __restrict__ X,
    const float* __restrict__ Wr, const float* __restrict__ Wz, const float* __restrict__ Wh,
    const float* __restrict__ br, const float* __restrict__ bz, const float* __restrict__ bh,
    float* __restrict__ ax)
{
  __shared__ float sX[16][64];   // [k][t]
  __shared__ float sW[16][64];   // [k][row]

  const int gl = blockIdx.z, l = gl / 3, g = gl % 3;
  const float* W    = (g == 0 ? Wr : (g == 1 ? Wz : Wh)) + (size_t)l * HD * (2 * HD) + HD;
  const float* bias = (g == 0 ? br : (g == 1 ? bz : bh)) + l * HD;
  const int t0 = blockIdx.y * 64, r0 = blockIdx.x * 64;
  const int tid = threadIdx.x;
  const int tx = tid & 15;
  const int ty = tid >> 4;
  const int lt = tid >> 2;
  const int lk = (tid & 3) * 4;

  float acc[4][4] = {};

  for (int k0 = 0; k0 < HD; k0 += 16) {
    float4 xv = *reinterpret_cast<const float4*>(&X[(size_t)(t0 + lt) * HD + k0 + lk]);
    float4 wv = *reinterpret_cast<const float4*>(&W[(size_t)(r0 + lt) * (2 * HD) + k0 + lk]);
    __syncthreads();
    sX[lk + 0][lt] = xv.x; sX[lk + 1][lt] = xv.y; sX[lk + 2][lt] = xv.z; sX[lk + 3][lt] = xv.w;
    sW[lk + 0][lt] = wv.x; sW[lk + 1][lt] = wv.y; sW[lk + 2][lt] = wv.z; sW[lk + 3][lt] = wv.w;
    __syncthreads();
#pragma unroll
    for (int k = 0; k < 16; ++k) {
      float4 a = *reinterpret_cast<const float4*>(&sX[k][ty * 4]);
      float4 b = *reinterpret_cast<const float4*>(&sW[k][tx * 4]);
      const float av[4] = {a.x, a.y, a.z, a.w};
      const float bv[4] = {b.x, b.y, b.z, b.w};
#pragma unroll
      for (int i = 0; i < 4; ++i)
#pragma unroll
        for (int j = 0; j < 4; ++j)
          acc[i][j] += av[i] * bv[j];
    }
  }

  float4 bb = *reinterpret_cast<const float4*>(&bias[r0 + tx * 4]);
  const float bv[4] = {bb.x, bb.y, bb.z, bb.w};
#pragma unroll
  for (int i = 0; i < 4; ++i) {
    float4 o;
    o.x = acc[i][0] + bv[0]; o.y = acc[i][1] + bv[1];
    o.z = acc[i][2] + bv[2]; o.w = acc[i][3] + bv[3];
    *reinterpret_cast<float4*>(
        &ax[((size_t)gl * SEQ + t0 + ty * 4 + i) * HD + r0 + tx * 4]) = o;
  }
}

// ---------------------------------------------------------------------------
// Phase B: 4096-step serial scan on 32 CUs, tagged dataflow (r11 layout).
// hpack / rhpack: [2 parity][8 mirrors][1024 u32] (64 KB each).
//   h entering step u : parity u&1, tag u   (memset 0 == step-0 init, h=0)
//   r*h of step u     : parity u&1, tag u+1
//   h leaving step u  : parity (u+1)&1, tag u+1
// Overwrite safety (r6 proof): a producer reaching a same-parity rewrite
// transitively proves every CU consumed the 2-steps-older generation.
// Thread = (row = tid>>4 of 32, kchunk = tid&15); wave owns 4 rows.
// Gate results computed redundantly by all 16 lanes of a row group
// (butterfly reduce; fp32 h-carry replicated, identical arithmetic ->
// deterministic), enabling the wave-cooperative dwordx4 publish.
// ---------------------------------------------------------------------------
__global__ void __launch_bounds__(TPB) gru_seq_kernel(
    const float* __restrict__ Wr, const float* __restrict__ Wz, const float* __restrict__ Wh,
    const float* __restrict__ ax,
    unsigned* __restrict__ hpack, unsigned* __restrict__ rhpack,
    float* __restrict__ outp)
{
  __shared__ unsigned sH[SLDS];    // staged h, bf16 pairs, swizzled
  __shared__ unsigned sRH[SLDS];   // staged r*h

  const int wg   = blockIdx.x;
  const int tid  = threadIdx.x;
  const int rloc = tid >> 4;              // 0..31 local row
  const int grow = wg * RPC + rloc;       // global row 0..1023
  const int kcIdx = tid & 15;
  const int kc   = kcIdx * KPT;           // k-chunk base
  const int lane = tid & 63;              // lane within wave
  const int wave = tid >> 6;              // 0..7
  const int pubrow = wg * RPC + wave * 4; // wave's first published row
  const bool lead = (kcIdx == 0);
  const int mymir = (wg & (NMIR - 1)) * HD;   // 4 CUs share each mirror

  unsigned wr_[32], wz_[32], wh_[32];     // current-layer weights, bf16 x2
  auto load_layer = [&](int l) {
    const size_t off = ((size_t)l * HD + grow) * (size_t)(2 * HD) + kc;
    load_gate(Wr + off, wr_);
    load_gate(Wz + off, wz_);
    load_gate(Wh + off, wh_);
  };
  load_layer(0);

  float hreg = 0.0f;                      // fp32 h carry, replicated x16
  float zv = 0.0f;
  // ax scalars: all 16 lanes of a row group load the same address (broadcast)
  float axr  = ax[(size_t)0 * SEQ * HD + grow];
  float axz  = ax[(size_t)1 * SEQ * HD + grow];
  float axh_ = ax[(size_t)2 * SEQ * HD + grow];

  for (int u = 0; u < NSTEP; ++u) {
    if (u == SEQ) load_layer(1);          // one-time layer switch
    const int pb  = (u & 1) * NMIR * HD;
    const int pbn = ((u + 1) & 1) * NMIR * HD;

    // ---- phase 1: poll h; r-dot; publish r*h; z-dot in store shadow -----
    if (tid < 256) {
      u32x4 v = poll4(&hpack[pb + mymir + 4 * tid], (unsigned)u);
      const int lp = 2 * tid;
      sH[swz(lp)]     = (v.y << 16) | (v.x & 0xFFFFu);   // bf16 pair (lo,hi)
      sH[swz(lp + 1)] = (v.w << 16) | (v.z & 0xFFFFu);
    }
    __syncthreads();                      // S1
    {
      const unsigned* hp = &sH[kcIdx * 33];
      float sr = 0.0f;
#pragma unroll
      for (int m = 0; m < 32; ++m) {
        const unsigned hpair = hp[m];
        const unsigned a = wr_[m];
        sr = fmaf(__uint_as_float(a << 16), __uint_as_float(hpair << 16), sr);
        sr = fmaf(__uint_as_float(a & 0xFFFF0000u),
                  __uint_as_float(hpair & 0xFFFF0000u), sr);
      }
      sr = red16(sr);
      const float rg = 1.0f / (1.0f + expf(-(sr + axr)));
      wave_publish(rhpack + pb, packbf(rg * hreg, (unsigned)(u + 1)),
                   lane, pubrow);
      // z-dot runs while the r*h store flies (needed only in phase 2)
      float sz = 0.0f;
#pragma unroll
      for (int m = 0; m < 32; ++m) {
        const unsigned hpair = hp[m];
        const unsigned b = wz_[m];
        sz = fmaf(__uint_as_float(b << 16), __uint_as_float(hpair << 16), sz);
        sz = fmaf(__uint_as_float(b & 0xFFFF0000u),
                  __uint_as_float(hpair & 0xFFFF0000u), sz);
      }
      sz = red16(sz);
      zv = 1.0f / (1.0f + expf(-(sz + axz)));
    }

    // ---- phase 2: poll r*h; hh-dot; blend; publish h ----------------------
    if (tid < 256) {
      u32x4 v = poll4(&rhpack[pb + mymir + 4 * tid], (unsigned)(u + 1));
      const int lp = 2 * tid;
      sRH[swz(lp)]     = (v.y << 16) | (v.x & 0xFFFFu);
      sRH[swz(lp + 1)] = (v.w << 16) | (v.z & 0xFFFFu);
    }
    __syncthreads();                      // S2
    {
      const unsigned* rp = &sRH[kcIdx * 33];
      float sh = 0.0f;
#pragma unroll
      for (int m = 0; m < 32; ++m) {
        const unsigned rpair = rp[m];
        const unsigned c = wh_[m];
        sh = fmaf(__uint_as_float(c << 16), __uint_as_float(rpair << 16), sh);
        sh = fmaf(__uint_as_float(c & 0xFFFF0000u),
                  __uint_as_float(rpair & 0xFFFF0000u), sh);
      }
      sh = red16(sh);
      const float hh = tanhf(sh + axh_);
      const float hn = (1.0f - zv) * hreg + zv * hh;    // fp32 carry
      hreg = hn;
      wave_publish(hpack + pbn, packbf(hn, (unsigned)(u + 1)), lane, pubrow);
      if (u == NSTEP - 1 && lead) {       // (output, hidden) identical
        outp[grow] = hn;
        outp[HD + grow] = hn;
      }
      // prefetch ax for step u+1 (drained by the next poll's pre-drain,
      // overlapped with producer->consumer flight)
      const int un = (u + 1 < NSTEP) ? u + 1 : u;
      const int ln = un >> 11, tn = un & (SEQ - 1);
      axr  = ax[(((size_t)ln * 3 + 0) * SEQ + tn) * HD + grow];
      axz  = ax[(((size_t)ln * 3 + 1) * SEQ + tn) * HD + grow];
      axh_ = ax[(((size_t)ln * 3 + 2) * SEQ + tn) * HD + grow];
    }
  }
}

// ---------------------------------------------------------------------------
extern "C" void kernel_launch(void* const* d_in, const int* in_sizes, int n_in,
                              void* d_out, int out_size, void* d_ws, size_t ws_size,
                              hipStream_t stream) {
  const float* emb = (const float*)d_in[0];
  const float* Wr  = (const float*)d_in[1];
  const float* br  = (const float*)d_in[2];
  const float* Wz  = (const float*)d_in[3];
  const float* bz  = (const float*)d_in[4];
  const float* Wh  = (const float*)d_in[5];
  const float* bh  = (const float*)d_in[6];
  float* outp = (float*)d_out;

  float*    ws     = (float*)d_ws;
  float*    ax     = ws;                                  // 6*SEQ*HD fp32 = 50.3 MB
  unsigned* hpack  = (unsigned*)(ws + (size_t)6 * SEQ * HD); // [2][8][1024] u32
  unsigned* rhpack = hpack + 2 * NMIR * HD;               // [2][8][1024] u32

  // Deterministic tag state each call: zero both parities of both mirrored
  // buffers (parity-0 tag 0 == "h entering step 0", value bf16(0)).
  hipMemsetAsync(hpack, 0, 4 * NMIR * HD * sizeof(unsigned), stream);

  // Phase A: x-part contributions + bias, all gates/layers (parallel GEMM)
  dim3 g1(HD / 64, SEQ / 64, 6);
  ax_gemm_kernel<<<g1, 256, 0, stream>>>(emb, Wr, Wz, Wh, br, bz, bh, ax);

  // Phase B: serial scan on 32 CUs (trivially co-resident; cooperative
  // launch keeps the guarantee explicit).
  void* args[] = {(void*)&Wr, (void*)&Wz, (void*)&Wh, (void*)&ax,
                  (void*)&hpack, (void*)&rhpack, (void*)&outp};
  hipLaunchCooperativeKernel((const void*)gru_seq_kernel, dim3(NBLK), dim3(TPB),
                             args, 0, stream);
}